// Round 16
// baseline (4622.636 us; speedup 1.0000x reference)
//
#include <hip/hip_runtime.h>
#include <hip/hip_bf16.h>

// Problem constants: B=256, T=512, D=64, H=256, C=10
#define Tt  512
#define Dd  64
#define CC  10
#define NG  4     // batch-groups interleaved per WG

typedef short  short8 __attribute__((ext_vector_type(8)));
typedef __bf16 bf16x8 __attribute__((ext_vector_type(8)));
typedef float  f32x4  __attribute__((ext_vector_type(4)));
typedef int    int4v  __attribute__((ext_vector_type(4)));

__device__ __forceinline__ unsigned short f2bf(float f) {
    unsigned u = __builtin_bit_cast(unsigned, f);
    u += 0x7fffu + ((u >> 16) & 1u);   // RNE
    return (unsigned short)(u >> 16);
}
__device__ __forceinline__ float bf2f(unsigned short s) {
    unsigned u = ((unsigned)s) << 16;
    return __builtin_bit_cast(float, u);
}
__device__ __forceinline__ float sigf(float x) {
    return __builtin_amdgcn_rcpf(1.0f + __expf(-x));
}
__device__ __forceinline__ float tanh_fast(float x) {
    return 1.0f - 2.0f * __builtin_amdgcn_rcpf(1.0f + __expf(2.0f * x));
}

// ---------------------------------------------------------------------------
// Pre-permute weights into per-lane MFMA A-fragment order (bf16).
// elem index = ((nf*10 + ks)*64 + lane)*8 + j
//   nf = h16*4 + gate;  k = ks*32 + (lane>>4)*8 + j  (k<256 -> W_hh else W_ih)
//   row = lane&15 -> n_orig = gate*256 + h16*16 + row
// ---------------------------------------------------------------------------
__global__ void prep_weights(const float* __restrict__ W_ih,
                             const float* __restrict__ W_hh,
                             unsigned short* __restrict__ Wc) {
    int id = blockIdx.x * blockDim.x + threadIdx.x;   // 0 .. 327679
    int j    = id & 7;
    int lane = (id >> 3) & 63;
    int rest = id >> 9;            // 0..639
    int ks   = rest % 10;
    int nf   = rest / 10;
    int k    = ks * 32 + ((lane >> 4) << 3) + j;
    int row  = lane & 15;
    int h16  = nf >> 2;
    int g    = nf & 3;
    int n_orig = g * 256 + h16 * 16 + row;
    float v = (k < 256) ? W_hh[n_orig * 256 + k]
                        : W_ih[n_orig * 64 + (k - 256)];
    Wc[id] = f2bf(v);
}

// biasp[h16*64 + g*16 + i] = b_ih[g*256+h16*16+i] + b_hh[...]  (i = hidx%16)
__global__ void prep_bias(const float* __restrict__ b_ih,
                          const float* __restrict__ b_hh,
                          float* __restrict__ biasp) {
    int tid = blockIdx.x * blockDim.x + threadIdx.x;  // 1024 threads
    if (tid < 1024) {
        int h16 = tid >> 6, g = (tid >> 4) & 3, i = tid & 15;
        int n_orig = g * 256 + h16 * 16 + i;
        biasp[tid] = b_ih[n_orig] + b_hh[n_orig];
    }
}

// ---------------------------------------------------------------------------
// Persistent LSTM, transposed GEMM (Z^T = W_cat @ [h;x]), 4-WAY INTERLEAVED.
// Grid 16 WGs = 4 sets x 4 hidx-parts. WG(set,p) round-robins 4 batch-groups
// bg = set*4+q (16 batches each); wave w owns h16 = p*4+w for ALL its groups
// (weights shared across groups -> zero extra weight cost). Per-group
// protocol = R14-proven: poll flag -> ONE fused asm block (8 parallel
// sc0sc1 dwordx4 loads + single vmcnt(0)) -> MFMA -> u64 agent atomic
// exchange -> barrier -> relaxed agent atomicAdd. No fence in the loop.
// Group q's ~2.1us handoff latency hides under the other 3 groups' segments.
// ---------------------------------------------------------------------------
__global__ __launch_bounds__(256, 1) void lstm_persist(
    const float* __restrict__ x,
    const unsigned short* __restrict__ Wc,
    const float* __restrict__ biasp,
    unsigned short* __restrict__ h0buf,   // [256 batch][256 hidx] bf16
    unsigned short* __restrict__ h1buf,
    unsigned int* __restrict__ arrive,
    const float* __restrict__ W_out,
    const float* __restrict__ b_out,
    float* __restrict__ out)
{
    const int tid  = threadIdx.x;
    const int lane = tid & 63;
    const int w    = tid >> 6;
    const int set  = blockIdx.x & 3;    // group-set 0..3
    const int p    = blockIdx.x >> 2;   // hidx part 0..3
    const int l15  = lane & 15;
    const int lhi  = lane >> 4;

    const int h16 = p * 4 + w;          // 0..15 (16-hidx chunk)

    // --- weights + bias (plain cached loads; L2 stays warm all loop) -------
    bf16x8 wfrag[10][4];
    #pragma unroll
    for (int ks = 0; ks < 10; ++ks)
        #pragma unroll
        for (int g = 0; g < 4; ++g)
            wfrag[ks][g] = __builtin_bit_cast(bf16x8,
                *reinterpret_cast<const short8*>(
                    Wc + (((h16 * 4 + g) * 10 + ks) * 64 + lane) * 8));
    f32x4 bias_r[4];
    #pragma unroll
    for (int g = 0; g < 4; ++g)
        bias_r[g] = __builtin_bit_cast(f32x4,
            *reinterpret_cast<const float4*>(biasp + h16 * 64 + g * 16 + lhi * 4));

    // --- per-group state (statically indexed after unroll) -----------------
    int           batch[NG];
    const float*  xrow[NG];
    unsigned int* cntq[NG];
    f32x4         creg[NG];
    float4        xq[NG][4];
    #pragma unroll
    for (int q = 0; q < NG; ++q) {
        int bg   = set * NG + q;
        batch[q] = bg * 16 + l15;
        xrow[q]  = x + (size_t)batch[q] * (Tt * Dd) + lhi * 8;
        cntq[q]  = arrive + bg * 32;
        creg[q]  = (f32x4){0.f, 0.f, 0.f, 0.f};
        xq[q][0] = *reinterpret_cast<const float4*>(xrow[q]);
        xq[q][1] = *reinterpret_cast<const float4*>(xrow[q] + 4);
        xq[q][2] = *reinterpret_cast<const float4*>(xrow[q] + 32);
        xq[q][3] = *reinterpret_cast<const float4*>(xrow[q] + 36);
    }

    for (int t = 0; t < Tt; ++t) {
        #pragma unroll
        for (int q = 0; q < NG; ++q) {
            // 1) x contribution (B-fragment from x; A = weights)
            f32x4 acc[4];
            #pragma unroll
            for (int g = 0; g < 4; ++g) acc[g] = bias_r[g];
            {
                float4 x0 = xq[q][0], x1 = xq[q][1], x2 = xq[q][2], x3 = xq[q][3];
                short8 a8 = (short8){ (short)f2bf(x0.x), (short)f2bf(x0.y),
                                      (short)f2bf(x0.z), (short)f2bf(x0.w),
                                      (short)f2bf(x1.x), (short)f2bf(x1.y),
                                      (short)f2bf(x1.z), (short)f2bf(x1.w) };
                short8 a9 = (short8){ (short)f2bf(x2.x), (short)f2bf(x2.y),
                                      (short)f2bf(x2.z), (short)f2bf(x2.w),
                                      (short)f2bf(x3.x), (short)f2bf(x3.y),
                                      (short)f2bf(x3.z), (short)f2bf(x3.w) };
                bf16x8 bv8 = __builtin_bit_cast(bf16x8, a8);
                bf16x8 bv9 = __builtin_bit_cast(bf16x8, a9);
                #pragma unroll
                for (int g = 0; g < 4; ++g) {
                    acc[g] = __builtin_amdgcn_mfma_f32_16x16x32_bf16(wfrag[8][g], bv8, acc[g], 0, 0, 0);
                    acc[g] = __builtin_amdgcn_mfma_f32_16x16x32_bf16(wfrag[9][g], bv9, acc[g], 0, 0, 0);
                }
            }

            // 2) poll group flag, then ONE fused block: 8 MALL loads + wait
            if (t > 0) {
                const unsigned target = 4u * (unsigned)t;
                if (lane == 0) {
                    while (__hip_atomic_load(cntq[q], __ATOMIC_RELAXED,
                                             __HIP_MEMORY_SCOPE_AGENT) < target) {}
                }
                __builtin_amdgcn_sched_barrier(0);   // loads stay below poll
                const unsigned short* hin = (t & 1) ? h1buf : h0buf;
                const void* haddr = hin + batch[q] * 256 + lhi * 8;
                int4v v0, v1, v2, v3, v4, v5, v6, v7;
                asm volatile(
                    "global_load_dwordx4 %0, %8, off sc0 sc1\n\t"
                    "global_load_dwordx4 %1, %8, off offset:64 sc0 sc1\n\t"
                    "global_load_dwordx4 %2, %8, off offset:128 sc0 sc1\n\t"
                    "global_load_dwordx4 %3, %8, off offset:192 sc0 sc1\n\t"
                    "global_load_dwordx4 %4, %8, off offset:256 sc0 sc1\n\t"
                    "global_load_dwordx4 %5, %8, off offset:320 sc0 sc1\n\t"
                    "global_load_dwordx4 %6, %8, off offset:384 sc0 sc1\n\t"
                    "global_load_dwordx4 %7, %8, off offset:448 sc0 sc1\n\t"
                    "s_waitcnt vmcnt(0)"
                    : "=&v"(v0), "=&v"(v1), "=&v"(v2), "=&v"(v3),
                      "=&v"(v4), "=&v"(v5), "=&v"(v6), "=&v"(v7)
                    : "v"(haddr)
                    : "memory");
                int4v hvv[8] = { v0, v1, v2, v3, v4, v5, v6, v7 };
                #pragma unroll
                for (int ks = 0; ks < 8; ++ks) {
                    bf16x8 bv = __builtin_bit_cast(bf16x8, hvv[ks]);
                    #pragma unroll
                    for (int g = 0; g < 4; ++g)
                        acc[g] = __builtin_amdgcn_mfma_f32_16x16x32_bf16(
                            wfrag[ks][g], bv, acc[g], 0, 0, 0);
                }
            }

            // 3) gates + c/h update; pack 4 consecutive-hidx h -> u64 SWAP
            unsigned short* hout = ((t + 1) & 1) ? h1buf : h0buf;
            unsigned long long hpack = 0;
            #pragma unroll
            for (int r = 0; r < 4; ++r) {
                float cn = sigf(acc[1][r]) * creg[q][r] + sigf(acc[0][r]) * tanh_fast(acc[2][r]);
                float hn = sigf(acc[3][r]) * tanh_fast(cn);
                creg[q][r] = cn;
                hpack |= (unsigned long long)f2bf(hn) << (16 * r);
            }
            {
                unsigned long long* hp = reinterpret_cast<unsigned long long*>(
                    hout + batch[q] * 256 + h16 * 16 + lhi * 4);
                (void)__hip_atomic_exchange(hp, hpack, __ATOMIC_RELAXED,
                                            __HIP_MEMORY_SCOPE_AGENT);
            }

            // 4) prefetch x(t+1) for this group (plain cached)
            if (t + 1 < Tt) {
                const float* xp = xrow[q] + (size_t)(t + 1) * Dd;
                xq[q][0] = *reinterpret_cast<const float4*>(xp);
                xq[q][1] = *reinterpret_cast<const float4*>(xp + 4);
                xq[q][2] = *reinterpret_cast<const float4*>(xp + 32);
                xq[q][3] = *reinterpret_cast<const float4*>(xp + 36);
            }

            // 5) publish this group: barrier drains the swap, relaxed add
            __syncthreads();
            if (tid == 0) {
                __hip_atomic_fetch_add(cntq[q], 1u, __ATOMIC_RELAXED,
                                       __HIP_MEMORY_SCOPE_AGENT);
            }
        }
    }

    // --- output head: p==0 WGs handle their 4 groups (one-time acquire) ----
    if (p == 0) {
        #pragma unroll 1
        for (int q = 0; q < NG; ++q) {
            if (lane == 0) {
                while (__hip_atomic_load(cntq[q], __ATOMIC_RELAXED,
                                         __HIP_MEMORY_SCOPE_AGENT) < 4u * Tt) {}
            }
            __builtin_amdgcn_fence(__ATOMIC_ACQUIRE, "agent");
            const unsigned short* hT = h0buf;   // Tt even -> final h in buf 0
            #pragma unroll 1
            for (int rr = 0; rr < 4; ++rr) {
                int row = (set * NG + q) * 16 + w * 4 + rr;
                ushort4 hu = *reinterpret_cast<const ushort4*>(hT + row * 256 + lane * 4);
                float f0 = bf2f(hu.x), f1 = bf2f(hu.y), f2 = bf2f(hu.z), f3 = bf2f(hu.w);
                #pragma unroll 1
                for (int cls = 0; cls < CC; ++cls) {
                    float4 wv = *reinterpret_cast<const float4*>(W_out + cls * 256 + lane * 4);
                    float pr = f0 * wv.x + f1 * wv.y + f2 * wv.z + f3 * wv.w;
                    #pragma unroll
                    for (int off = 32; off > 0; off >>= 1) pr += __shfl_down(pr, off);
                    if (lane == 0) out[row * CC + cls] = sigf(pr + b_out[cls]);
                }
            }
        }
    }
}

extern "C" void kernel_launch(void* const* d_in, const int* in_sizes, int n_in,
                              void* d_out, int out_size, void* d_ws, size_t ws_size,
                              hipStream_t stream) {
    const float* x     = (const float*)d_in[0];
    const float* W_ih  = (const float*)d_in[1];
    const float* W_hh  = (const float*)d_in[2];
    const float* b_ih  = (const float*)d_in[3];
    const float* b_hh  = (const float*)d_in[4];
    const float* W_out = (const float*)d_in[5];
    const float* b_out = (const float*)d_in[6];
    float* out = (float*)d_out;

    // workspace layout (~924 KB)
    char* ws = (char*)d_ws;
    unsigned short* Wc    = (unsigned short*)(ws);            // 655360 B
    float*          biasp = (float*)(ws + 655360);            //   4096 B
    unsigned short* h0    = (unsigned short*)(ws + 659456);   // 131072 B
    unsigned short* h1    = (unsigned short*)(ws + 790528);   // 131072 B
    unsigned int*   arr   = (unsigned int*)(ws + 921600);     //   2048 B

    hipLaunchKernelGGL(prep_weights, dim3(1280), dim3(256), 0, stream, W_ih, W_hh, Wc);
    hipLaunchKernelGGL(prep_bias,    dim3(4),    dim3(256), 0, stream, b_ih, b_hh, biasp);
    hipMemsetAsync(arr, 0, 2048, stream);

    hipLaunchKernelGGL(lstm_persist, dim3(16), dim3(256), 0, stream,
                       x, Wc, biasp, h0, h1, arr, W_out, b_out, out);
}

// Round 17
// 1328.420 us; speedup vs baseline: 3.4798x; 3.4798x over previous
//
#include <hip/hip_runtime.h>
#include <hip/hip_bf16.h>

// Problem constants: B=256, T=512, D=64, H=256, C=10
#define Tt  512
#define Dd  64
#define CC  10

typedef short  short8 __attribute__((ext_vector_type(8)));
typedef __bf16 bf16x8 __attribute__((ext_vector_type(8)));
typedef float  f32x4  __attribute__((ext_vector_type(4)));
typedef int    int4v  __attribute__((ext_vector_type(4)));

__device__ __forceinline__ unsigned short f2bf(float f) {
    unsigned u = __builtin_bit_cast(unsigned, f);
    u += 0x7fffu + ((u >> 16) & 1u);   // RNE
    return (unsigned short)(u >> 16);
}
__device__ __forceinline__ float bf2f(unsigned short s) {
    unsigned u = ((unsigned)s) << 16;
    return __builtin_bit_cast(float, u);
}
__device__ __forceinline__ float sigf(float x) {
    return __builtin_amdgcn_rcpf(1.0f + __expf(-x));
}
__device__ __forceinline__ float tanh_fast(float x) {
    return 1.0f - 2.0f * __builtin_amdgcn_rcpf(1.0f + __expf(2.0f * x));
}

// ---------------------------------------------------------------------------
// Pre-permute weights into per-lane MFMA A-fragment order (bf16).
// elem index = ((nf*10 + ks)*64 + lane)*8 + j
//   nf = h16*4 + gate;  k = ks*32 + (lane>>4)*8 + j  (k<256 -> W_hh else W_ih)
//   row = lane&15 -> n_orig = gate*256 + h16*16 + row
// ---------------------------------------------------------------------------
__global__ void prep_weights(const float* __restrict__ W_ih,
                             const float* __restrict__ W_hh,
                             unsigned short* __restrict__ Wc) {
    int id = blockIdx.x * blockDim.x + threadIdx.x;   // 0 .. 327679
    int j    = id & 7;
    int lane = (id >> 3) & 63;
    int rest = id >> 9;            // 0..639
    int ks   = rest % 10;
    int nf   = rest / 10;
    int k    = ks * 32 + ((lane >> 4) << 3) + j;
    int row  = lane & 15;
    int h16  = nf >> 2;
    int g    = nf & 3;
    int n_orig = g * 256 + h16 * 16 + row;
    float v = (k < 256) ? W_hh[n_orig * 256 + k]
                        : W_ih[n_orig * 64 + (k - 256)];
    Wc[id] = f2bf(v);
}

// biasp[h16*64 + g*16 + i] = b_ih[g*256+h16*16+i] + b_hh[...]  (i = hidx%16)
__global__ void prep_bias(const float* __restrict__ b_ih,
                          const float* __restrict__ b_hh,
                          float* __restrict__ biasp) {
    int tid = blockIdx.x * blockDim.x + threadIdx.x;  // 1024 threads
    if (tid < 1024) {
        int h16 = tid >> 6, g = (tid >> 4) & 3, i = tid & 15;
        int n_orig = g * 256 + h16 * 16 + i;
        biasp[tid] = b_ih[n_orig] + b_hh[n_orig];
    }
}

// ---------------------------------------------------------------------------
// Persistent LSTM, transposed GEMM (Z^T = W_cat @ [h;x]), 1-WAVE WGs + LDS
// weights. Grid 256 WGs = 16 batch-groups x 16 hidx-parts; WG(bg,pp) is ONE
// wave owning h16 = pp (16 hidx x 4 gates x 16 batches of group bg).
// Weights (40 KB/wave) + bias live in LDS -> the per-step VMEM queue holds
// ONLY {poll, fused h-load, swap, x-prefetch}, so handoff RTTs are not
// inflated by 160 remat loads (R14's hidden cost; R13's "+v" pin was the
// wrong fix). No __syncthreads anywhere in the loop (1 wave): publish =
// u64 agent swap -> s_waitcnt vmcnt(0) -> lane0 relaxed agent atomicAdd
// (counter target 16t, 16 producer waves/group). Consumer = R14-proven
// poll + ONE fused asm block (8 parallel sc0sc1 dwordx4 + single vmcnt(0)).
// ---------------------------------------------------------------------------
__global__ __launch_bounds__(64, 1) void lstm_persist(
    const float* __restrict__ x,
    const unsigned short* __restrict__ Wc,
    const float* __restrict__ biasp,
    unsigned short* __restrict__ h0buf,   // [256 batch][256 hidx] bf16
    unsigned short* __restrict__ h1buf,
    unsigned int* __restrict__ arrive,
    const float* __restrict__ W_out,
    const float* __restrict__ b_out,
    float* __restrict__ out)
{
    const int lane = threadIdx.x;       // 0..63
    const int bg   = blockIdx.x & 15;   // batch group 0..15
    const int pp   = blockIdx.x >> 4;   // hidx part  0..15
    const int l15  = lane & 15;
    const int lhi  = lane >> 4;

    const int h16   = pp;               // 16-hidx chunk
    const int batch = bg * 16 + l15;    // this lane's batch column

    unsigned int* cnt  = arrive + bg * 32;             // 128 B apart per group
    const float*  xrow = x + (size_t)batch * (Tt * Dd) + lhi * 8;

    // --- LDS: 40 weight fragments (1 KB each) + 64 bias floats -------------
    __shared__ unsigned short wlds[40 * 512];   // 40 KB
    __shared__ float          blds[64];         // 256 B
    #pragma unroll
    for (int ks = 0; ks < 10; ++ks)
        #pragma unroll
        for (int g = 0; g < 4; ++g) {
            uint4 v = *reinterpret_cast<const uint4*>(
                Wc + (((h16 * 4 + g) * 10 + ks) * 64 + lane) * 8);
            *reinterpret_cast<uint4*>(
                reinterpret_cast<char*>(wlds) + (ks * 4 + g) * 1024 + lane * 16) = v;
        }
    blds[lane] = biasp[h16 * 64 + lane];
    __syncthreads();

    // x(t=0)
    float4 xq0 = *reinterpret_cast<const float4*>(xrow);
    float4 xq1 = *reinterpret_cast<const float4*>(xrow + 4);
    float4 xq2 = *reinterpret_cast<const float4*>(xrow + 32);
    float4 xq3 = *reinterpret_cast<const float4*>(xrow + 36);

    f32x4 creg = (f32x4){0.f, 0.f, 0.f, 0.f};

    // weight-fragment reader (ds_read_b128)
    auto WF = [&](int ks, int g) -> bf16x8 {
        return __builtin_bit_cast(bf16x8, *reinterpret_cast<const uint4*>(
            reinterpret_cast<const char*>(wlds) + (ks * 4 + g) * 1024 + lane * 16));
    };

    for (int t = 0; t < Tt; ++t) {
        // 1) x contribution (B-fragment from x; A = weights from LDS)
        f32x4 acc[4];
        #pragma unroll
        for (int g = 0; g < 4; ++g)
            acc[g] = __builtin_bit_cast(f32x4,
                *reinterpret_cast<const float4*>(&blds[g * 16 + lhi * 4]));
        {
            short8 a8 = (short8){ (short)f2bf(xq0.x), (short)f2bf(xq0.y),
                                  (short)f2bf(xq0.z), (short)f2bf(xq0.w),
                                  (short)f2bf(xq1.x), (short)f2bf(xq1.y),
                                  (short)f2bf(xq1.z), (short)f2bf(xq1.w) };
            short8 a9 = (short8){ (short)f2bf(xq2.x), (short)f2bf(xq2.y),
                                  (short)f2bf(xq2.z), (short)f2bf(xq2.w),
                                  (short)f2bf(xq3.x), (short)f2bf(xq3.y),
                                  (short)f2bf(xq3.z), (short)f2bf(xq3.w) };
            bf16x8 bv8 = __builtin_bit_cast(bf16x8, a8);
            bf16x8 bv9 = __builtin_bit_cast(bf16x8, a9);
            #pragma unroll
            for (int g = 0; g < 4; ++g) {
                acc[g] = __builtin_amdgcn_mfma_f32_16x16x32_bf16(WF(8, g), bv8, acc[g], 0, 0, 0);
                acc[g] = __builtin_amdgcn_mfma_f32_16x16x32_bf16(WF(9, g), bv9, acc[g], 0, 0, 0);
            }
        }

        // 2) poll group flag, then ONE fused block: 8 parallel MALL loads
        if (t > 0) {
            const unsigned target = 16u * (unsigned)t;
            if (lane == 0) {
                while (__hip_atomic_load(cnt, __ATOMIC_RELAXED,
                                         __HIP_MEMORY_SCOPE_AGENT) < target) {}
            }
            __builtin_amdgcn_sched_barrier(0);   // loads stay below the poll
            const unsigned short* hin = (t & 1) ? h1buf : h0buf;
            const void* haddr = hin + batch * 256 + lhi * 8;   // 16B aligned
            int4v v0, v1, v2, v3, v4, v5, v6, v7;
            asm volatile(
                "global_load_dwordx4 %0, %8, off sc0 sc1\n\t"
                "global_load_dwordx4 %1, %8, off offset:64 sc0 sc1\n\t"
                "global_load_dwordx4 %2, %8, off offset:128 sc0 sc1\n\t"
                "global_load_dwordx4 %3, %8, off offset:192 sc0 sc1\n\t"
                "global_load_dwordx4 %4, %8, off offset:256 sc0 sc1\n\t"
                "global_load_dwordx4 %5, %8, off offset:320 sc0 sc1\n\t"
                "global_load_dwordx4 %6, %8, off offset:384 sc0 sc1\n\t"
                "global_load_dwordx4 %7, %8, off offset:448 sc0 sc1\n\t"
                "s_waitcnt vmcnt(0)"
                : "=&v"(v0), "=&v"(v1), "=&v"(v2), "=&v"(v3),
                  "=&v"(v4), "=&v"(v5), "=&v"(v6), "=&v"(v7)
                : "v"(haddr)
                : "memory");
            int4v hvv[8] = { v0, v1, v2, v3, v4, v5, v6, v7 };
            #pragma unroll
            for (int ks = 0; ks < 8; ++ks) {
                bf16x8 bv = __builtin_bit_cast(bf16x8, hvv[ks]);
                #pragma unroll
                for (int g = 0; g < 4; ++g)
                    acc[g] = __builtin_amdgcn_mfma_f32_16x16x32_bf16(
                        WF(ks, g), bv, acc[g], 0, 0, 0);
            }
        }

        // 3) gates + c/h update; pack 4 consecutive-hidx h -> one u64 SWAP
        unsigned short* hout = ((t + 1) & 1) ? h1buf : h0buf;
        unsigned long long hpack = 0;
        #pragma unroll
        for (int r = 0; r < 4; ++r) {
            float cn = sigf(acc[1][r]) * creg[r] + sigf(acc[0][r]) * tanh_fast(acc[2][r]);
            float hn = sigf(acc[3][r]) * tanh_fast(cn);
            creg[r] = cn;
            hpack |= (unsigned long long)f2bf(hn) << (16 * r);
        }
        {
            unsigned long long* hp = reinterpret_cast<unsigned long long*>(
                hout + batch * 256 + h16 * 16 + lhi * 4);
            (void)__hip_atomic_exchange(hp, hpack, __ATOMIC_RELAXED,
                                        __HIP_MEMORY_SCOPE_AGENT);
        }

        // 4) prefetch x for t+1 (plain cached; drained by the vmcnt below)
        if (t + 1 < Tt) {
            const float* xp = xrow + (size_t)(t + 1) * Dd;
            xq0 = *reinterpret_cast<const float4*>(xp);
            xq1 = *reinterpret_cast<const float4*>(xp + 4);
            xq2 = *reinterpret_cast<const float4*>(xp + 32);
            xq3 = *reinterpret_cast<const float4*>(xp + 36);
        }

        // 5) publish: drain the swap (whole-wave op), then relaxed add.
        //    No barrier needed — this WG is one wave.
        asm volatile("s_waitcnt vmcnt(0)" ::: "memory");
        __builtin_amdgcn_sched_barrier(0);
        if (lane == 0) {
            __hip_atomic_fetch_add(cnt, 1u, __ATOMIC_RELAXED,
                                   __HIP_MEMORY_SCOPE_AGENT);
        }
    }

    // --- output head: pp==0 WGs handle their group's 16 rows ---------------
    if (pp == 0) {
        if (lane == 0) {
            while (__hip_atomic_load(cnt, __ATOMIC_RELAXED,
                                     __HIP_MEMORY_SCOPE_AGENT) < 16u * Tt) {}
        }
        __builtin_amdgcn_fence(__ATOMIC_ACQUIRE, "agent");
        const unsigned short* hT = h0buf;   // Tt even -> final h in buf 0
        #pragma unroll 1
        for (int rr = 0; rr < 16; ++rr) {
            int row = bg * 16 + rr;
            ushort4 hu = *reinterpret_cast<const ushort4*>(hT + row * 256 + lane * 4);
            float f0 = bf2f(hu.x), f1 = bf2f(hu.y), f2 = bf2f(hu.z), f3 = bf2f(hu.w);
            #pragma unroll 1
            for (int cls = 0; cls < CC; ++cls) {
                float4 wv = *reinterpret_cast<const float4*>(W_out + cls * 256 + lane * 4);
                float pr = f0 * wv.x + f1 * wv.y + f2 * wv.z + f3 * wv.w;
                #pragma unroll
                for (int off = 32; off > 0; off >>= 1) pr += __shfl_down(pr, off);
                if (lane == 0) out[row * CC + cls] = sigf(pr + b_out[cls]);
            }
        }
    }
}

extern "C" void kernel_launch(void* const* d_in, const int* in_sizes, int n_in,
                              void* d_out, int out_size, void* d_ws, size_t ws_size,
                              hipStream_t stream) {
    const float* x     = (const float*)d_in[0];
    const float* W_ih  = (const float*)d_in[1];
    const float* W_hh  = (const float*)d_in[2];
    const float* b_ih  = (const float*)d_in[3];
    const float* b_hh  = (const float*)d_in[4];
    const float* W_out = (const float*)d_in[5];
    const float* b_out = (const float*)d_in[6];
    float* out = (float*)d_out;

    // workspace layout (~924 KB)
    char* ws = (char*)d_ws;
    unsigned short* Wc    = (unsigned short*)(ws);            // 655360 B
    float*          biasp = (float*)(ws + 655360);            //   4096 B
    unsigned short* h0    = (unsigned short*)(ws + 659456);   // 131072 B
    unsigned short* h1    = (unsigned short*)(ws + 790528);   // 131072 B
    unsigned int*   arr   = (unsigned int*)(ws + 921600);     //   2048 B

    hipLaunchKernelGGL(prep_weights, dim3(1280), dim3(256), 0, stream, W_ih, W_hh, Wc);
    hipLaunchKernelGGL(prep_bias,    dim3(4),    dim3(256), 0, stream, b_ih, b_hh, biasp);
    hipMemsetAsync(arr, 0, 2048, stream);

    hipLaunchKernelGGL(lstm_persist, dim3(256), dim3(64), 0, stream,
                       x, Wc, biasp, h0, h1, arr, W_out, b_out, out);
}